// Round 10
// baseline (82.136 us; speedup 1.0000x reference)
//
#include <hip/hip_runtime.h>

#define ROWS 65536
#define BE   8192
#define NT   9                  // B tiles: 0-3 S-e, 4 = [S-m | Y2-m | pad], 5-8 Y2-e
#define KT   8                  // K = 256

typedef float  f32x4  __attribute__((ext_vector_type(4)));
typedef __bf16 bf16x8 __attribute__((ext_vector_type(8)));

// ---- workspace layout (byte offsets) ----
#define SU_OFF   0                                   // ROWS*64 u32 (lo=sE, hi=y2e) 16.8 MB
#define SMU_OFF  (SU_OFF + (size_t)ROWS * 64 * 4)    // ROWS u32 (lo=sM, hi=y2m)
#define SEG_OFF  (SMU_OFF + ROWS * 4)                // BE uint2 {start,len}
#define SP_OFF   (SEG_OFF + BE * 8)                  // ROWS u32 : row -> sorted dest
#define ORD_OFF  (SP_OFF + ROWS * 4)                 // ROWS u32 : sorted dest -> row
#define WEF_OFF  (ORD_OFF + ROWS * 4)                // KT*NT*64 bf16x8 = 73728 B (global)

__device__ inline float bflo(unsigned u) { return __uint_as_float(u << 16); }
__device__ inline float bfhi(unsigned u) { return __uint_as_float(u & 0xffff0000u); }
__device__ inline unsigned pack2(float lo, float hi) {
    return (unsigned)__builtin_bit_cast(unsigned short, (__bf16)lo)
         | ((unsigned)__builtin_bit_cast(unsigned short, (__bf16)hi) << 16);
}

// blocks 0..7: per-batch LDS bucketize (hist+scan+fill). blocks 8..25: pack W'.
// wef[(g*NT+nt)*64+lane] = 8 bf16 of W'[nt*16+(lane&15)][g*32+(lane>>4)*8 ..]
//   tiles 0-3: W1+W2 ; tile 4: col0 = wm1+wm2, col1 = wm2 ; tiles 5-8: W2
__global__ __launch_bounds__(256) void prep_kernel(
    const int* __restrict__ idx, const float* __restrict__ we,
    const float* __restrict__ wm, char* __restrict__ ws) {

    const int bid = blockIdx.x;
    const int tid = threadIdx.x;

    if (bid >= 8) {                                  // ---- wef packing ----
        const int t  = (bid - 8) * 256 + tid;        // 0..4607
        const int fl = t & 63;
        const int f  = t >> 6;
        const int g  = f / NT, nt = f % NT;
        const int c  = fl & 15;
        const int k0 = (g << 5) + ((fl >> 4) << 3);
        bf16x8 v;
        if (nt == 4) {
#pragma unroll
            for (int i = 0; i < 8; ++i) {
                const float fv = (c == 0) ? wm[k0 + i] + wm[256 + k0 + i]
                               : (c == 1) ? wm[256 + k0 + i] : 0.f;
                v[i] = (__bf16)fv;
            }
        } else if (nt < 4) {
            const float* wr = we + (nt * 16 + c) * 512 + k0;
#pragma unroll
            for (int i = 0; i < 8; ++i) v[i] = (__bf16)(wr[i] + wr[256 + i]);
        } else {
            const float* wr = we + ((nt - 5) * 16 + c) * 512 + k0;
#pragma unroll
            for (int i = 0; i < 8; ++i) v[i] = (__bf16)wr[256 + i];
        }
        *(bf16x8*)((__bf16*)(ws + WEF_OFF) + (size_t)t * 8) = v;
        return;
    }

    // ---- bucketize batch bid ----
    __shared__ unsigned h[1028];
    const int l = tid & 63, w = tid >> 6;
    h[tid] = 0u; h[tid + 256] = 0u; h[tid + 512] = 0u; h[tid + 768] = 0u;
    __syncthreads();
    const int b13 = bid << 13;
    unsigned my[32];
#pragma unroll
    for (int i = 0; i < 32; ++i) my[i] = (unsigned)idx[b13 + (i << 8) + tid];
#pragma unroll
    for (int i = 0; i < 32; ++i) atomicAdd(&h[my[i]], 1u);
    __syncthreads();
    unsigned loc[4], s4 = 0;
#pragma unroll
    for (int i = 0; i < 4; ++i) { loc[i] = h[tid * 4 + i]; s4 += loc[i]; }
    unsigned inc = s4;
#pragma unroll
    for (int off = 1; off < 64; off <<= 1) {
        const unsigned v = __shfl_up(inc, off);
        if (l >= off) inc += v;
    }
    if (l == 63) h[1024 + w] = inc;
    __syncthreads();
    unsigned run = inc - s4;
    for (int ww = 0; ww < w; ++ww) run += h[1024 + ww];
    uint2* seg = (uint2*)(ws + SEG_OFF);
#pragma unroll
    for (int i = 0; i < 4; ++i) {
        seg[(bid << 10) + tid * 4 + i] = make_uint2((unsigned)b13 + run, loc[i]);
        h[tid * 4 + i] = run;                        // batch-local cursor
        run += loc[i];
    }
    __syncthreads();
    unsigned* sp    = (unsigned*)(ws + SP_OFF);
    unsigned* order = (unsigned*)(ws + ORD_OFF);
#pragma unroll 4
    for (int i = 0; i < 32; ++i) {
        const unsigned p   = atomicAdd(&h[my[i]], 1u);
        const unsigned row = (unsigned)(b13 + (i << 8) + tid);
        const unsigned d   = (unsigned)b13 + p;
        sp[row]  = d;
        order[d] = row;
    }
}

// GEMM: [65536 x 256] @ [256 x 144(pad)] -> packed su/smu scatter-written at sorted dest
__global__ __launch_bounds__(256) void gemm_kernel(
    const float* __restrict__ obs, char* __restrict__ ws) {

    const __bf16* wefg = (const __bf16*)(ws + WEF_OFF);
    const int tid = threadIdx.x;
    const int l   = tid & 63;
    const int rw0 = blockIdx.x * 128 + (tid >> 6) * 32;
    const int r0  = rw0 + (l & 15);
    const int r1  = r0 + 16;
    const int q8  = (l >> 4) << 3;

    f32x4 acc[2][NT];
#pragma unroll
    for (int a = 0; a < 2; ++a)
#pragma unroll
        for (int b = 0; b < NT; ++b) acc[a][b] = (f32x4){0.f, 0.f, 0.f, 0.f};

    const float* o0 = obs + (((size_t)r0) << 8) + q8;
    const float* o1 = obs + (((size_t)r1) << 8) + q8;

#pragma unroll
    for (int g = 0; g < KT; ++g) {
        const f32x4 oa0 = *(const f32x4*)(o0 + g * 32);
        const f32x4 ob0 = *(const f32x4*)(o0 + g * 32 + 4);
        const f32x4 oa1 = *(const f32x4*)(o1 + g * 32);
        const f32x4 ob1 = *(const f32x4*)(o1 + g * 32 + 4);
        bf16x8 A0, A1;
#pragma unroll
        for (int i = 0; i < 4; ++i) {
            A0[i] = (__bf16)oa0[i];  A0[4 + i] = (__bf16)ob0[i];
            A1[i] = (__bf16)oa1[i];  A1[4 + i] = (__bf16)ob1[i];
        }
#pragma unroll
        for (int nt = 0; nt < NT; ++nt) {
            const bf16x8 bb = *(const bf16x8*)(wefg + (size_t)(((g * NT + nt) << 6) + l) * 8);
            acc[0][nt] = __builtin_amdgcn_mfma_f32_16x16x32_bf16(A0, bb, acc[0][nt], 0, 0, 0);
            acc[1][nt] = __builtin_amdgcn_mfma_f32_16x16x32_bf16(A1, bb, acc[1][nt], 0, 0, 0);
        }
    }

    unsigned* su  = (unsigned*)(ws + SU_OFF);
    unsigned* smu = (unsigned*)(ws + SMU_OFF);
    const unsigned* sp = (const unsigned*)(ws + SP_OFF);
    const int cgrp = (l >> 4) << 2;
    const int c16  = l & 15;
#pragma unroll
    for (int rt = 0; rt < 2; ++rt)
#pragma unroll
        for (int j = 0; j < 4; ++j) {
            const int row = rw0 + rt * 16 + cgrp + j;
            const unsigned dp = sp[row];                       // 16-lane broadcast load
            const float y2mv = __shfl(acc[rt][4][j], l | 1);   // tile-4 col 1 = Y2-m
#pragma unroll
            for (int nt = 0; nt < 4; ++nt)
                su[((size_t)dp << 6) + (nt << 4) + c16] = pack2(acc[rt][nt][j], acc[rt][nt + 5][j]);
            if (c16 == 0) smu[dp] = pack2(acc[rt][4][j], y2mv);
        }
}

// tail: one wave per 4 buckets; contiguous segment reads; final math fused.
__global__ __launch_bounds__(256) void tail_kernel(
    const float* __restrict__ mask, const float* __restrict__ bmp,
    const float* __restrict__ bep, char* __restrict__ ws, float* __restrict__ out) {

    const unsigned* su    = (const unsigned*)(ws + SU_OFF);
    const unsigned* smu   = (const unsigned*)(ws + SMU_OFF);
    const uint2*    seg   = (const uint2*)(ws + SEG_OFF);
    const unsigned* order = (const unsigned*)(ws + ORD_OFF);
    const int wgid = blockIdx.x * 4 + (threadIdx.x >> 6);
    const int l    = threadIdx.x & 63;
    const float bm  = bmp[0];
    const float bel = bep[l];

    for (int s = 0; s < 4; ++s) {
        const int bucket = wgid * 4 + s;
        const uint2 sg = seg[bucket];
        const unsigned start = sg.x, len = sg.y;
        if (len == 0) continue;                      // wave-uniform branch
        float ae = 0.f, am = 0.f;
        for (unsigned i = 0; i < len; ++i)
            ae += bfhi(su[((size_t)(start + i) << 6) + l]);
        for (unsigned i = l; i < len; i += 64) am += bfhi(smu[start + i]);
#pragma unroll
        for (int off = 1; off < 64; off <<= 1) am += __shfl_xor(am, off);
        const float inv = 1.f / (float)len;
        const float me = ae * inv, mm = am * inv;
        for (unsigned i = 0; i < len; ++i) {
            const unsigned d   = start + i;
            const unsigned row = order[d];
            const unsigned uu  = su[((size_t)d << 6) + l];
            const float mk = mask[row];
            const float m  = bflo(smu[d]) - mm + bm;
            const float gg = mk / (1.f + __expf(-m));
            out[(size_t)ROWS + ((size_t)row << 6) + l] = (bflo(uu) - me + bel) * gg * mk;
            if (l == 0) out[row] = gg;
        }
    }
}

extern "C" void kernel_launch(void* const* d_in, const int* in_sizes, int n_in,
                              void* d_out, int out_size, void* d_ws, size_t ws_size,
                              hipStream_t stream) {
    (void)in_sizes; (void)n_in; (void)out_size; (void)ws_size;
    const float* obs  = (const float*)d_in[0];
    const float* mask = (const float*)d_in[1];
    // d_in[2] = incidence: one-hot of idx, never read (saves 268 MB of traffic)
    const int*   idx  = (const int*)d_in[3];
    const float* w_m  = (const float*)d_in[4];
    const float* b_m  = (const float*)d_in[5];
    const float* w_e  = (const float*)d_in[6];
    const float* b_e  = (const float*)d_in[7];
    char*  ws   = (char*)d_ws;
    float* outp = (float*)d_out;

    prep_kernel<<<26, 256, 0, stream>>>(idx, w_e, w_m, ws);
    gemm_kernel<<<512, 256, 0, stream>>>(obs, ws);
    tail_kernel<<<512, 256, 0, stream>>>(mask, b_m, b_e, ws, outp);
}

// Round 11
// 48.994 us; speedup vs baseline: 1.6765x; 1.6765x over previous
//
#include <hip/hip_runtime.h>

#define B_ 8
#define N_ 8192
#define E_ 1024
#define ROWS (B_ * N_)          // 65536
#define BE (B_ * E_)            // 8192
#define NT 10                   // 0..4 = S=(W1+W2) proj, 5..9 = Y2=W2 proj (col 64 = membrane)
#define KT 8                    // K = 256

typedef float  f32x4  __attribute__((ext_vector_type(4)));
typedef __bf16 bf16x8 __attribute__((ext_vector_type(8)));

// ---- workspace layout (byte offsets). Bulk arrays in NATURAL row order. ----
#define SE16_OFF  0                            // ROWS*64 bf16 (8.39 MB)
#define SM16_OFF  (SE16_OFF + ROWS * 64 * 2)   // ROWS bf16
#define Y2E_OFF   (SM16_OFF + ROWS * 2)        // ROWS*64 bf16 (8.39 MB)
#define Y2M_OFF   (Y2E_OFF + ROWS * 64 * 2)    // ROWS bf16
#define SEG_OFF   (Y2M_OFF + ROWS * 2)         // BE uint2 {start,len}
#define ORD_OFF   (SEG_OFF + BE * 8)           // ROWS u32 : sorted dest -> row
#define WEF_OFF   (ORD_OFF + ROWS * 4)         // KT*NT*64*8 bf16 (80 KB)

__device__ inline float bflo(unsigned u) { return __uint_as_float(u << 16); }
__device__ inline float bfhi(unsigned u) { return __uint_as_float(u & 0xffff0000u); }

// blocks 0..7: per-batch LDS bucketize (hist+scan+fill, zero global atomics).
// blocks 8..12: pack W' fragments.
// wef[((kt*NT+nt)*64+lane)*8+i] = W'[(nt%5)*16+(lane&15)][kt*32+(lane>>4)*8+i]
//   grp = nt/5: 0 -> W1+W2 (S), 1 -> W2 (Y2); row 64 = w_m, 65..79 zero.
__global__ __launch_bounds__(1024) void bucketize_kernel(
    const int* __restrict__ idx, const float* __restrict__ we,
    const float* __restrict__ wm, char* __restrict__ ws) {

    const int bid = blockIdx.x;
    if (bid >= 8) {                            // ---- wef packing ----
        const int t = (bid - 8) * 1024 + threadIdx.x;   // 0..5119
        if (t >= KT * NT * 64) return;
        __bf16* wef = (__bf16*)(ws + WEF_OFF);
        const int lane = t & 63;
        const int nt = (t >> 6) % NT;
        const int kt = t / (NT * 64);
        const int grp = nt / 5;
        const int r   = (nt % 5) * 16 + (lane & 15);
        const int k0  = kt * 32 + (lane >> 4) * 8;
        bf16x8 v;
#pragma unroll
        for (int i = 0; i < 8; ++i) {
            const int k = k0 + i;
            float f = 0.f;
            if (r < 64)       f = grp ? we[r * 512 + 256 + k] : we[r * 512 + k] + we[r * 512 + 256 + k];
            else if (r == 64) f = grp ? wm[256 + k]           : wm[k] + wm[256 + k];
            v[i] = (__bf16)f;
        }
        *(bf16x8*)(wef + (size_t)t * 8) = v;
        return;
    }

    // ---- per-batch bucketize: batch b, 1024 threads, LDS hist/scan/cursor ----
    __shared__ unsigned h[1024];
    __shared__ unsigned wpart[16];
    const int b = bid;
    const int t = threadIdx.x;
    const int lane = t & 63;
    const int w = t >> 6;

    h[t] = 0u;
    __syncthreads();

    unsigned my[8];
#pragma unroll
    for (int i = 0; i < 8; ++i) my[i] = (unsigned)idx[(b << 13) + (i << 10) + t];
#pragma unroll
    for (int i = 0; i < 8; ++i) atomicAdd(&h[my[i]], 1u);
    __syncthreads();

    const unsigned v = h[t];
    unsigned inc = v;
#pragma unroll
    for (int off = 1; off < 64; off <<= 1) {
        const unsigned u = __shfl_up(inc, off);
        if (lane >= off) inc += u;
    }
    if (lane == 63) wpart[w] = inc;
    __syncthreads();
    unsigned add = 0;
    for (int ww = 0; ww < w; ++ww) add += wpart[ww];
    const unsigned base = add + inc - v;               // exclusive scan within batch

    ((uint2*)(ws + SEG_OFF))[(b << 10) + t] = (uint2){(unsigned)(b << 13) + base, v};
    __syncthreads();
    h[t] = base;                                       // reuse hist as cursor
    __syncthreads();

    unsigned* order = (unsigned*)(ws + ORD_OFF);
#pragma unroll
    for (int i = 0; i < 8; ++i) {
        const unsigned p = atomicAdd(&h[my[i]], 1u);
        order[(b << 13) + p] = (unsigned)((b << 13) + (i << 10) + t);
    }
}

// GEMM: [65536 x 256] @ [256 x 160(pad)] -> sE/sM + y2e/y2m (bf16), written at
// NATURAL row order (fully coalesced; no sortpos gather, no scatter).
__global__ __launch_bounds__(256) void gemm_kernel(
    const float* __restrict__ obs, char* __restrict__ ws) {

    const __bf16* wefg = (const __bf16*)(ws + WEF_OFF);
    const int tid = threadIdx.x;
    const int l   = tid & 63;
    const int rw0 = blockIdx.x * 128 + (tid >> 6) * 32;
    const int r0  = rw0 + (l & 15);
    const int r1  = r0 + 16;
    const int q8  = (l >> 4) << 3;

    f32x4 acc[2][NT];
#pragma unroll
    for (int a = 0; a < 2; ++a)
#pragma unroll
        for (int b = 0; b < NT; ++b) acc[a][b] = (f32x4){0.f, 0.f, 0.f, 0.f};

    const float* o0 = obs + (((size_t)r0) << 8) + q8;
    const float* o1 = obs + (((size_t)r1) << 8) + q8;

#pragma unroll
    for (int g = 0; g < KT; ++g) {
        const f32x4 oa0 = *(const f32x4*)(o0 + g * 32);
        const f32x4 ob0 = *(const f32x4*)(o0 + g * 32 + 4);
        const f32x4 oa1 = *(const f32x4*)(o1 + g * 32);
        const f32x4 ob1 = *(const f32x4*)(o1 + g * 32 + 4);
        bf16x8 A0, A1;
#pragma unroll
        for (int i = 0; i < 4; ++i) {
            A0[i] = (__bf16)oa0[i];  A0[4 + i] = (__bf16)ob0[i];
            A1[i] = (__bf16)oa1[i];  A1[4 + i] = (__bf16)ob1[i];
        }
#pragma unroll
        for (int nt = 0; nt < NT; ++nt) {
            const bf16x8 bb = *(const bf16x8*)(wefg + (size_t)(((g * NT + nt) << 6) + l) * 8);
            acc[0][nt] = __builtin_amdgcn_mfma_f32_16x16x32_bf16(A0, bb, acc[0][nt], 0, 0, 0);
            acc[1][nt] = __builtin_amdgcn_mfma_f32_16x16x32_bf16(A1, bb, acc[1][nt], 0, 0, 0);
        }
    }

    __bf16* sE  = (__bf16*)(ws + SE16_OFF);
    __bf16* sM  = (__bf16*)(ws + SM16_OFF);
    __bf16* y2e = (__bf16*)(ws + Y2E_OFF);
    __bf16* y2m = (__bf16*)(ws + Y2M_OFF);

    const int cgrp = (l >> 4) << 2;
    const int c16  = l & 15;
#pragma unroll
    for (int rt = 0; rt < 2; ++rt) {
#pragma unroll
        for (int j = 0; j < 4; ++j) {
            const int row = rw0 + rt * 16 + cgrp + j;
#pragma unroll
            for (int nt = 0; nt < 4; ++nt) {
                sE [((size_t)row << 6) + (nt << 4) + c16] = (__bf16)acc[rt][nt][j];
                y2e[((size_t)row << 6) + (nt << 4) + c16] = (__bf16)acc[rt][5 + nt][j];
            }
            if (c16 == 0) {
                sM [row] = (__bf16)acc[rt][4][j];
                y2m[row] = (__bf16)acc[rt][9][j];
            }
        }
    }
}

// tail: one wave per bucket (8192 waves). Phase 1: order-indirect segment-sum of y2
// -> in-register means. Phase 2: final math for member rows, write g_n / e_n.
__global__ __launch_bounds__(256) void tail_kernel(
    const float* __restrict__ mask, const float* __restrict__ bmp,
    const float* __restrict__ bep, const char* __restrict__ ws,
    float* __restrict__ out) {

    const int bucket = blockIdx.x * 4 + (threadIdx.x >> 6);
    const int l  = threadIdx.x & 63;
    const int lc = l & 31;          // col pair (2lc, 2lc+1)
    const int hi = l >> 5;          // member parity

    const uint2 sg = ((const uint2*)(ws + SEG_OFF))[bucket];
    const unsigned start = sg.x, len = sg.y;
    if (len == 0) return;                              // wave-uniform, safe

    const unsigned*       ordu = (const unsigned*)(ws + ORD_OFF);
    const unsigned*       y2eu = (const unsigned*)(ws + Y2E_OFF);
    const unsigned short* y2m  = (const unsigned short*)(ws + Y2M_OFF);

    float ax = 0.f, ay = 0.f;
    for (unsigned i = hi; i < len; i += 2) {
        const unsigned row = ordu[start + i];
        const unsigned u = y2eu[(size_t)row * 32 + lc];
        ax += bflo(u); ay += bfhi(u);
    }
    ax += __shfl_xor(ax, 32);
    ay += __shfl_xor(ay, 32);

    float mm = 0.f;
    for (unsigned i = l; i < len; i += 64) mm += bflo(y2m[ordu[start + i]]);
#pragma unroll
    for (int off = 1; off < 64; off <<= 1) mm += __shfl_xor(mm, off);

    const float inv = 1.f / (float)len;
    const float meL = ax * inv, meH = ay * inv, mM = mm * inv;
    const float bm  = bmp[0];
    const float beL = bep[2 * lc], beH = bep[2 * lc + 1];

    const unsigned*       sEu  = (const unsigned*)(ws + SE16_OFF);
    const unsigned short* sM16 = (const unsigned short*)(ws + SM16_OFF);

    for (unsigned i = hi; i < len; i += 2) {
        const unsigned row = ordu[start + i];
        const unsigned u   = sEu[(size_t)row * 32 + lc];
        const float sm = bflo(sM16[row]);
        const float mk = mask[row];
        const float m  = sm - mM + bm;
        const float g  = mk / (1.f + __expf(-m));
        float2 e;
        e.x = (bflo(u) - meL + beL) * g * mk;
        e.y = (bfhi(u) - meH + beH) * g * mk;
        *(float2*)(out + (size_t)ROWS + ((size_t)row << 6) + 2 * lc) = e;
        if (lc == 0) out[row] = g;
    }
}

extern "C" void kernel_launch(void* const* d_in, const int* in_sizes, int n_in,
                              void* d_out, int out_size, void* d_ws, size_t ws_size,
                              hipStream_t stream) {
    (void)in_sizes; (void)n_in; (void)out_size; (void)ws_size;
    const float* obs  = (const float*)d_in[0];
    const float* mask = (const float*)d_in[1];
    // d_in[2] = incidence: one-hot of idx, never read (saves 268 MB of traffic)
    const int*   idx  = (const int*)d_in[3];
    const float* w_m  = (const float*)d_in[4];
    const float* b_m  = (const float*)d_in[5];
    const float* w_e  = (const float*)d_in[6];
    const float* b_e  = (const float*)d_in[7];

    char* ws = (char*)d_ws;

    bucketize_kernel<<<13, 1024, 0, stream>>>(idx, w_e, w_m, ws);
    gemm_kernel<<<ROWS / 128, 256, 0, stream>>>(obs, ws);
    tail_kernel<<<BE / 4, 256, 0, stream>>>(mask, b_m, b_e, ws, (float*)d_out);
}

// Round 12
// 47.163 us; speedup vs baseline: 1.7415x; 1.0388x over previous
//
#include <hip/hip_runtime.h>

#define B_ 8
#define N_ 8192
#define E_ 1024
#define ROWS (B_ * N_)          // 65536
#define BE (B_ * E_)            // 8192
#define NT 10                   // 0..4 = S=(W1+W2) proj, 5..9 = Y2=W2 proj (col 64 = membrane)
#define KT 8                    // K = 256

typedef float  f32x4  __attribute__((ext_vector_type(4)));
typedef __bf16 bf16x8 __attribute__((ext_vector_type(8)));

// ---- workspace layout (byte offsets). Bulk arrays indexed by SORTED dest. ----
#define SE16_OFF  0                            // ROWS*64 bf16 (8.39 MB)
#define SM16_OFF  (SE16_OFF + ROWS * 64 * 2)   // ROWS bf16
#define Y2E_OFF   (SM16_OFF + ROWS * 2)        // ROWS*64 bf16 (8.39 MB)
#define Y2M_OFF   (Y2E_OFF + ROWS * 64 * 2)    // ROWS bf16
#define SEG_OFF   (Y2M_OFF + ROWS * 2)         // BE uint2 {start,len}
#define SP_OFF    (SEG_OFF + BE * 8)           // ROWS u32 : row -> sorted dest
#define ORD_OFF   (SP_OFF + ROWS * 4)          // ROWS u32 : sorted dest -> row
#define WEF_OFF   (ORD_OFF + ROWS * 4)         // KT*NT*64*8 bf16 (80 KB)

__device__ inline float bflo(unsigned u) { return __uint_as_float(u << 16); }
__device__ inline float bfhi(unsigned u) { return __uint_as_float(u & 0xffff0000u); }

// blocks 0..7: per-batch LDS bucketize (hist+scan+fill, zero global atomics).
// blocks 8..12: pack W' fragments.
// wef[((kt*NT+nt)*64+lane)*8+i] = W'[(nt%5)*16+(lane&15)][kt*32+(lane>>4)*8+i]
//   grp = nt/5: 0 -> W1+W2 (S), 1 -> W2 (Y2); row 64 = w_m, 65..79 zero.
__global__ __launch_bounds__(1024) void bucketize_kernel(
    const int* __restrict__ idx, const float* __restrict__ we,
    const float* __restrict__ wm, char* __restrict__ ws) {

    const int bid = blockIdx.x;
    if (bid >= 8) {                            // ---- wef packing ----
        const int t = (bid - 8) * 1024 + threadIdx.x;   // 0..5119
        if (t >= KT * NT * 64) return;
        __bf16* wef = (__bf16*)(ws + WEF_OFF);
        const int lane = t & 63;
        const int nt = (t >> 6) % NT;
        const int kt = t / (NT * 64);
        const int grp = nt / 5;
        const int r   = (nt % 5) * 16 + (lane & 15);
        const int k0  = kt * 32 + (lane >> 4) * 8;
        bf16x8 v;
#pragma unroll
        for (int i = 0; i < 8; ++i) {
            const int k = k0 + i;
            float f = 0.f;
            if (r < 64)       f = grp ? we[r * 512 + 256 + k] : we[r * 512 + k] + we[r * 512 + 256 + k];
            else if (r == 64) f = grp ? wm[256 + k]           : wm[k] + wm[256 + k];
            v[i] = (__bf16)f;
        }
        *(bf16x8*)(wef + (size_t)t * 8) = v;
        return;
    }

    // ---- per-batch bucketize: batch b, 1024 threads, LDS hist/scan/cursor ----
    __shared__ unsigned h[1024];
    __shared__ unsigned wpart[16];
    const int b = bid;
    const int t = threadIdx.x;
    const int lane = t & 63;
    const int w = t >> 6;

    h[t] = 0u;
    __syncthreads();

    unsigned my[8];
#pragma unroll
    for (int i = 0; i < 8; ++i) my[i] = (unsigned)idx[(b << 13) + (i << 10) + t];
#pragma unroll
    for (int i = 0; i < 8; ++i) atomicAdd(&h[my[i]], 1u);
    __syncthreads();

    const unsigned v = h[t];
    unsigned inc = v;
#pragma unroll
    for (int off = 1; off < 64; off <<= 1) {
        const unsigned u = __shfl_up(inc, off);
        if (lane >= off) inc += u;
    }
    if (lane == 63) wpart[w] = inc;
    __syncthreads();
    unsigned add = 0;
    for (int ww = 0; ww < w; ++ww) add += wpart[ww];
    const unsigned base = add + inc - v;               // exclusive scan within batch

    ((uint2*)(ws + SEG_OFF))[(b << 10) + t] = (uint2){(unsigned)(b << 13) + base, v};
    __syncthreads();
    h[t] = base;                                       // reuse hist as cursor
    __syncthreads();

    unsigned* sortpos = (unsigned*)(ws + SP_OFF);
    unsigned* order   = (unsigned*)(ws + ORD_OFF);
#pragma unroll
    for (int i = 0; i < 8; ++i) {
        const unsigned p   = atomicAdd(&h[my[i]], 1u);
        const unsigned row = (unsigned)(b << 13) + (i << 10) + t;
        const unsigned d   = (unsigned)(b << 13) + p;
        sortpos[row] = d;
        order[d]     = row;
    }
}

// GEMM: [65536 x 256] @ [256 x 160(pad)] -> sE/sM + y2e/y2m (bf16), scatter-written
// at the sorted dest. 16 rows per wave, 1024 blocks: 2x resident waves vs 32-row
// version (acc VGPRs halved) to hide the HBM obs stream latency.
__global__ __launch_bounds__(256) void gemm_kernel(
    const float* __restrict__ obs, char* __restrict__ ws) {

    const __bf16* wefg = (const __bf16*)(ws + WEF_OFF);
    const int tid = threadIdx.x;
    const int l   = tid & 63;
    const int rw0 = blockIdx.x * 64 + (tid >> 6) * 16;
    const int r0  = rw0 + (l & 15);
    const int q8  = (l >> 4) << 3;

    f32x4 acc[NT];
#pragma unroll
    for (int b = 0; b < NT; ++b) acc[b] = (f32x4){0.f, 0.f, 0.f, 0.f};

    const float* o0 = obs + (((size_t)r0) << 8) + q8;

#pragma unroll
    for (int g = 0; g < KT; ++g) {
        const f32x4 oa0 = *(const f32x4*)(o0 + g * 32);
        const f32x4 ob0 = *(const f32x4*)(o0 + g * 32 + 4);
        bf16x8 A0;
#pragma unroll
        for (int i = 0; i < 4; ++i) {
            A0[i] = (__bf16)oa0[i];  A0[4 + i] = (__bf16)ob0[i];
        }
#pragma unroll
        for (int nt = 0; nt < NT; ++nt) {
            const bf16x8 bb = *(const bf16x8*)(wefg + (size_t)(((g * NT + nt) << 6) + l) * 8);
            acc[nt] = __builtin_amdgcn_mfma_f32_16x16x32_bf16(A0, bb, acc[nt], 0, 0, 0);
        }
    }

    __bf16* sE  = (__bf16*)(ws + SE16_OFF);
    __bf16* sM  = (__bf16*)(ws + SM16_OFF);
    __bf16* y2e = (__bf16*)(ws + Y2E_OFF);
    __bf16* y2m = (__bf16*)(ws + Y2M_OFF);
    const unsigned* sortpos = (const unsigned*)(ws + SP_OFF);

    const int cgrp = (l >> 4) << 2;
    const int c16  = l & 15;
#pragma unroll
    for (int j = 0; j < 4; ++j) {
        const int row = rw0 + cgrp + j;
        const unsigned dp = sortpos[row];          // 16-lane broadcast load
#pragma unroll
        for (int nt = 0; nt < 4; ++nt) {
            sE [((size_t)dp << 6) + (nt << 4) + c16] = (__bf16)acc[nt][j];
            y2e[((size_t)dp << 6) + (nt << 4) + c16] = (__bf16)acc[5 + nt][j];
        }
        if (c16 == 0) {
            sM [dp] = (__bf16)acc[4][j];
            y2m[dp] = (__bf16)acc[9][j];
        }
    }
}

// tail: one wave per bucket. Phase 1: contiguous segment-sum of y2 -> in-register means.
// Phase 2: apply final math to the bucket's member rows and write g_n / e_n.
__global__ __launch_bounds__(256) void tail_kernel(
    const float* __restrict__ mask, const float* __restrict__ bmp,
    const float* __restrict__ bep, const char* __restrict__ ws,
    float* __restrict__ out) {

    const int bucket = blockIdx.x * 4 + (threadIdx.x >> 6);
    const int l  = threadIdx.x & 63;
    const int lc = l & 31;          // col pair (2lc, 2lc+1)
    const int hi = l >> 5;          // member parity

    const uint2 sg = ((const uint2*)(ws + SEG_OFF))[bucket];
    const unsigned start = sg.x, len = sg.y;
    if (len == 0) return;                              // wave-uniform, safe

    const unsigned*       y2eu = (const unsigned*)(ws + Y2E_OFF);
    const unsigned short* y2m  = (const unsigned short*)(ws + Y2M_OFF);

    float ax = 0.f, ay = 0.f;
    for (unsigned i = hi; i < len; i += 2) {
        const unsigned u = y2eu[(size_t)(start + i) * 32 + lc];
        ax += bflo(u); ay += bfhi(u);
    }
    ax += __shfl_xor(ax, 32);
    ay += __shfl_xor(ay, 32);

    float mm = 0.f;
    for (unsigned i = l; i < len; i += 64) mm += bflo(y2m[start + i]);
#pragma unroll
    for (int off = 1; off < 64; off <<= 1) mm += __shfl_xor(mm, off);

    const float inv = 1.f / (float)len;
    const float meL = ax * inv, meH = ay * inv, mM = mm * inv;
    const float bm  = bmp[0];
    const float beL = bep[2 * lc], beH = bep[2 * lc + 1];

    const unsigned*       sEu  = (const unsigned*)(ws + SE16_OFF);
    const unsigned short* sM16 = (const unsigned short*)(ws + SM16_OFF);
    const unsigned*       ordu = (const unsigned*)(ws + ORD_OFF);

    for (unsigned i = hi; i < len; i += 2) {
        const unsigned d   = start + i;
        const unsigned row = ordu[d];
        const unsigned u   = sEu[(size_t)d * 32 + lc];
        const float sm = bflo(sM16[d]);
        const float mk = mask[row];
        const float m  = sm - mM + bm;
        const float g  = mk / (1.f + __expf(-m));
        float2 e;
        e.x = (bflo(u) - meL + beL) * g * mk;
        e.y = (bfhi(u) - meH + beH) * g * mk;
        *(float2*)(out + (size_t)ROWS + ((size_t)row << 6) + 2 * lc) = e;
        if (lc == 0) out[row] = g;
    }
}

extern "C" void kernel_launch(void* const* d_in, const int* in_sizes, int n_in,
                              void* d_out, int out_size, void* d_ws, size_t ws_size,
                              hipStream_t stream) {
    (void)in_sizes; (void)n_in; (void)out_size; (void)ws_size;
    const float* obs  = (const float*)d_in[0];
    const float* mask = (const float*)d_in[1];
    // d_in[2] = incidence: one-hot of idx, never read (saves 268 MB of traffic)
    const int*   idx  = (const int*)d_in[3];
    const float* w_m  = (const float*)d_in[4];
    const float* b_m  = (const float*)d_in[5];
    const float* w_e  = (const float*)d_in[6];
    const float* b_e  = (const float*)d_in[7];

    char* ws = (char*)d_ws;

    bucketize_kernel<<<13, 1024, 0, stream>>>(idx, w_e, w_m, ws);
    gemm_kernel<<<ROWS / 64, 256, 0, stream>>>(obs, ws);
    tail_kernel<<<BE / 4, 256, 0, stream>>>(mask, b_m, b_e, ws, (float*)d_out);
}

// Round 13
// 45.886 us; speedup vs baseline: 1.7900x; 1.0278x over previous
//
#include <hip/hip_runtime.h>

#define B_ 8
#define N_ 8192
#define E_ 1024
#define ROWS (B_ * N_)          // 65536
#define BE (B_ * E_)            // 8192
#define NT 10                   // 0..4 = S=(W1+W2) proj, 5..9 = Y2=W2 proj (col 64 = membrane)
#define KT 8                    // K = 256

typedef float  f32x4  __attribute__((ext_vector_type(4)));
typedef __bf16 bf16x8 __attribute__((ext_vector_type(8)));

// ---- workspace layout (byte offsets). Bulk arrays indexed by SORTED position. ----
#define SE16_OFF  0                            // ROWS*64 bf16 (8.39 MB)
#define SM16_OFF  (SE16_OFF + ROWS * 64 * 2)   // ROWS bf16
#define Y2E_OFF   (SM16_OFF + ROWS * 2)        // ROWS*64 bf16 (8.39 MB)
#define Y2M_OFF   (Y2E_OFF + ROWS * 64 * 2)    // ROWS bf16
#define SEG_OFF   (Y2M_OFF + ROWS * 2)         // BE uint2 {start,len}
#define ORD_OFF   (SEG_OFF + BE * 8)           // ROWS u32 : sorted position -> row
#define WEF_OFF   (ORD_OFF + ROWS * 4)         // KT*NT*64*8 bf16 (80 KB)

__device__ inline float bflo(unsigned u) { return __uint_as_float(u << 16); }
__device__ inline float bfhi(unsigned u) { return __uint_as_float(u & 0xffff0000u); }

// blocks 0..7: per-batch LDS bucketize (hist+scan+fill, zero global atomics).
// blocks 8..12: pack W' fragments.
// wef[((kt*NT+nt)*64+lane)*8+i] = W'[(nt%5)*16+(lane&15)][kt*32+(lane>>4)*8+i]
//   grp = nt/5: 0 -> W1+W2 (S), 1 -> W2 (Y2); row 64 = w_m, 65..79 zero.
__global__ __launch_bounds__(1024) void bucketize_kernel(
    const int* __restrict__ idx, const float* __restrict__ we,
    const float* __restrict__ wm, char* __restrict__ ws) {

    const int bid = blockIdx.x;
    if (bid >= 8) {                            // ---- wef packing ----
        const int t = (bid - 8) * 1024 + threadIdx.x;   // 0..5119
        if (t >= KT * NT * 64) return;
        __bf16* wef = (__bf16*)(ws + WEF_OFF);
        const int lane = t & 63;
        const int nt = (t >> 6) % NT;
        const int kt = t / (NT * 64);
        const int grp = nt / 5;
        const int r   = (nt % 5) * 16 + (lane & 15);
        const int k0  = kt * 32 + (lane >> 4) * 8;
        bf16x8 v;
#pragma unroll
        for (int i = 0; i < 8; ++i) {
            const int k = k0 + i;
            float f = 0.f;
            if (r < 64)       f = grp ? we[r * 512 + 256 + k] : we[r * 512 + k] + we[r * 512 + 256 + k];
            else if (r == 64) f = grp ? wm[256 + k]           : wm[k] + wm[256 + k];
            v[i] = (__bf16)f;
        }
        *(bf16x8*)(wef + (size_t)t * 8) = v;
        return;
    }

    // ---- per-batch bucketize: batch b, 1024 threads, LDS hist/scan/cursor ----
    __shared__ unsigned h[1024];
    __shared__ unsigned wpart[16];
    const int b = bid;
    const int t = threadIdx.x;
    const int lane = t & 63;
    const int w = t >> 6;

    h[t] = 0u;
    __syncthreads();

    unsigned my[8];
#pragma unroll
    for (int i = 0; i < 8; ++i) my[i] = (unsigned)idx[(b << 13) + (i << 10) + t];
#pragma unroll
    for (int i = 0; i < 8; ++i) atomicAdd(&h[my[i]], 1u);
    __syncthreads();

    const unsigned v = h[t];
    unsigned inc = v;
#pragma unroll
    for (int off = 1; off < 64; off <<= 1) {
        const unsigned u = __shfl_up(inc, off);
        if (lane >= off) inc += u;
    }
    if (lane == 63) wpart[w] = inc;
    __syncthreads();
    unsigned add = 0;
    for (int ww = 0; ww < w; ++ww) add += wpart[ww];
    const unsigned base = add + inc - v;               // exclusive scan within batch

    ((uint2*)(ws + SEG_OFF))[(b << 10) + t] = (uint2){(unsigned)(b << 13) + base, v};
    __syncthreads();
    h[t] = base;                                       // reuse hist as cursor
    __syncthreads();

    unsigned* order = (unsigned*)(ws + ORD_OFF);
#pragma unroll
    for (int i = 0; i < 8; ++i) {
        const unsigned p = atomicAdd(&h[my[i]], 1u);
        order[(b << 13) + p] = (unsigned)((b << 13) + (i << 10) + t);
    }
}

// GEMM over SORTED row order: lane gathers its obs row via order[] (random but
// full-line 128B reads); epilogue writes sE/sM/y2e/y2m fully contiguous at the
// block's sorted-position window. No scatter, no write-allocate waste.
__global__ __launch_bounds__(256) void gemm_kernel(
    const float* __restrict__ obs, char* __restrict__ ws) {

    const __bf16*   wefg = (const __bf16*)(ws + WEF_OFF);
    const unsigned* ordu = (const unsigned*)(ws + ORD_OFF);
    const int tid = threadIdx.x;
    const int l   = tid & 63;
    const int pw0 = blockIdx.x * 128 + (tid >> 6) * 32;   // sorted-position window
    const int q8  = (l >> 4) << 3;

    const unsigned r0 = ordu[pw0 + (l & 15)];             // natural rows to gather
    const unsigned r1 = ordu[pw0 + 16 + (l & 15)];

    f32x4 acc[2][NT];
#pragma unroll
    for (int a = 0; a < 2; ++a)
#pragma unroll
        for (int b = 0; b < NT; ++b) acc[a][b] = (f32x4){0.f, 0.f, 0.f, 0.f};

    const float* o0 = obs + (((size_t)r0) << 8) + q8;
    const float* o1 = obs + (((size_t)r1) << 8) + q8;

#pragma unroll
    for (int g = 0; g < KT; ++g) {
        const f32x4 oa0 = *(const f32x4*)(o0 + g * 32);
        const f32x4 ob0 = *(const f32x4*)(o0 + g * 32 + 4);
        const f32x4 oa1 = *(const f32x4*)(o1 + g * 32);
        const f32x4 ob1 = *(const f32x4*)(o1 + g * 32 + 4);
        bf16x8 A0, A1;
#pragma unroll
        for (int i = 0; i < 4; ++i) {
            A0[i] = (__bf16)oa0[i];  A0[4 + i] = (__bf16)ob0[i];
            A1[i] = (__bf16)oa1[i];  A1[4 + i] = (__bf16)ob1[i];
        }
#pragma unroll
        for (int nt = 0; nt < NT; ++nt) {
            const bf16x8 bb = *(const bf16x8*)(wefg + (size_t)(((g * NT + nt) << 6) + l) * 8);
            acc[0][nt] = __builtin_amdgcn_mfma_f32_16x16x32_bf16(A0, bb, acc[0][nt], 0, 0, 0);
            acc[1][nt] = __builtin_amdgcn_mfma_f32_16x16x32_bf16(A1, bb, acc[1][nt], 0, 0, 0);
        }
    }

    __bf16* sE  = (__bf16*)(ws + SE16_OFF);
    __bf16* sM  = (__bf16*)(ws + SM16_OFF);
    __bf16* y2e = (__bf16*)(ws + Y2E_OFF);
    __bf16* y2m = (__bf16*)(ws + Y2M_OFF);

    const int cgrp = (l >> 4) << 2;
    const int c16  = l & 15;
#pragma unroll
    for (int rt = 0; rt < 2; ++rt) {
#pragma unroll
        for (int j = 0; j < 4; ++j) {
            const int dp = pw0 + rt * 16 + cgrp + j;       // dest = sorted position
#pragma unroll
            for (int nt = 0; nt < 4; ++nt) {
                sE [((size_t)dp << 6) + (nt << 4) + c16] = (__bf16)acc[rt][nt][j];
                y2e[((size_t)dp << 6) + (nt << 4) + c16] = (__bf16)acc[rt][5 + nt][j];
            }
            if (c16 == 0) {
                sM [dp] = (__bf16)acc[rt][4][j];
                y2m[dp] = (__bf16)acc[rt][9][j];
            }
        }
    }
}

// tail: one wave per bucket. Phase 1: contiguous segment-sum of y2 -> in-register means.
// Phase 2: apply final math to the bucket's member rows and write g_n / e_n.
__global__ __launch_bounds__(256) void tail_kernel(
    const float* __restrict__ mask, const float* __restrict__ bmp,
    const float* __restrict__ bep, const char* __restrict__ ws,
    float* __restrict__ out) {

    const int bucket = blockIdx.x * 4 + (threadIdx.x >> 6);
    const int l  = threadIdx.x & 63;
    const int lc = l & 31;          // col pair (2lc, 2lc+1)
    const int hi = l >> 5;          // member parity

    const uint2 sg = ((const uint2*)(ws + SEG_OFF))[bucket];
    const unsigned start = sg.x, len = sg.y;
    if (len == 0) return;                              // wave-uniform, safe

    const unsigned*       y2eu = (const unsigned*)(ws + Y2E_OFF);
    const unsigned short* y2m  = (const unsigned short*)(ws + Y2M_OFF);

    float ax = 0.f, ay = 0.f;
    for (unsigned i = hi; i < len; i += 2) {
        const unsigned u = y2eu[(size_t)(start + i) * 32 + lc];
        ax += bflo(u); ay += bfhi(u);
    }
    ax += __shfl_xor(ax, 32);
    ay += __shfl_xor(ay, 32);

    float mm = 0.f;
    for (unsigned i = l; i < len; i += 64) mm += bflo(y2m[start + i]);
#pragma unroll
    for (int off = 1; off < 64; off <<= 1) mm += __shfl_xor(mm, off);

    const float inv = 1.f / (float)len;
    const float meL = ax * inv, meH = ay * inv, mM = mm * inv;
    const float bm  = bmp[0];
    const float beL = bep[2 * lc], beH = bep[2 * lc + 1];

    const unsigned*       sEu  = (const unsigned*)(ws + SE16_OFF);
    const unsigned short* sM16 = (const unsigned short*)(ws + SM16_OFF);
    const unsigned*       ordu = (const unsigned*)(ws + ORD_OFF);

    for (unsigned i = hi; i < len; i += 2) {
        const unsigned d   = start + i;
        const unsigned row = ordu[d];
        const unsigned u   = sEu[(size_t)d * 32 + lc];
        const float sm = bflo(sM16[d]);
        const float mk = mask[row];
        const float m  = sm - mM + bm;
        const float g  = mk / (1.f + __expf(-m));
        float2 e;
        e.x = (bflo(u) - meL + beL) * g * mk;
        e.y = (bfhi(u) - meH + beH) * g * mk;
        *(float2*)(out + (size_t)ROWS + ((size_t)row << 6) + 2 * lc) = e;
        if (lc == 0) out[row] = g;
    }
}

extern "C" void kernel_launch(void* const* d_in, const int* in_sizes, int n_in,
                              void* d_out, int out_size, void* d_ws, size_t ws_size,
                              hipStream_t stream) {
    (void)in_sizes; (void)n_in; (void)out_size; (void)ws_size;
    const float* obs  = (const float*)d_in[0];
    const float* mask = (const float*)d_in[1];
    // d_in[2] = incidence: one-hot of idx, never read (saves 268 MB of traffic)
    const int*   idx  = (const int*)d_in[3];
    const float* w_m  = (const float*)d_in[4];
    const float* b_m  = (const float*)d_in[5];
    const float* w_e  = (const float*)d_in[6];
    const float* b_e  = (const float*)d_in[7];

    char* ws = (char*)d_ws;

    bucketize_kernel<<<13, 1024, 0, stream>>>(idx, w_e, w_m, ws);
    gemm_kernel<<<ROWS / 128, 256, 0, stream>>>(obs, ws);
    tail_kernel<<<BE / 4, 256, 0, stream>>>(mask, b_m, b_e, ws, (float*)d_out);
}